// Round 4
// baseline (419.845 us; speedup 1.0000x reference)
//
#include <hip/hip_runtime.h>
#include <math.h>

#define B_ 8
#define T_ 1024
#define C_ 768
#define H_ 8
#define D_ 96
#define M_ (B_ * T_)     // 8192 tokens
#define N1_ (3 * C_)     // 2304

typedef __bf16 bf16x8 __attribute__((ext_vector_type(8)));
typedef float f32x4 __attribute__((ext_vector_type(4)));

__device__ __forceinline__ unsigned short f2bf(float f) {
  unsigned int u = __float_as_uint(f);
  u += 0x7FFF + ((u >> 16) & 1);          // round-to-nearest-even
  return (unsigned short)(u >> 16);
}

// ---------------------------------------------------------------------------
// fp32 -> bf16 elementwise (for x)
// ---------------------------------------------------------------------------
__global__ __launch_bounds__(256) void cvt_bf16_kernel(
    const float* __restrict__ in, unsigned short* __restrict__ out, int n) {
  int i = (blockIdx.x * 256 + threadIdx.x) * 4;
  if (i + 3 < n) {
    float4 v = *(const float4*)(in + i);
    ushort4 o;
    o.x = f2bf(v.x); o.y = f2bf(v.y); o.z = f2bf(v.z); o.w = f2bf(v.w);
    *(ushort4*)(out + i) = o;
  }
}

// ---------------------------------------------------------------------------
// W [Kd][Nd] fp32 -> WT [Nd][Kd] bf16
// ---------------------------------------------------------------------------
__global__ __launch_bounds__(256) void w_transpose_kernel(
    const float* __restrict__ W, unsigned short* __restrict__ WT,
    int Kd, int Nd) {
  __shared__ float Lt[32][33];
  const int r0 = blockIdx.x * 32;   // Kd
  const int c0 = blockIdx.y * 32;   // Nd
#pragma unroll
  for (int i = 0; i < 4; ++i) {
    int e = threadIdx.x + 256 * i;
    int r = e >> 5, c = e & 31;
    Lt[r][c] = W[(size_t)(r0 + r) * Nd + c0 + c];
  }
  __syncthreads();
#pragma unroll
  for (int i = 0; i < 4; ++i) {
    int e = threadIdx.x + 256 * i;
    int rr = e >> 5, cc = e & 31;
    WT[(size_t)(c0 + rr) * Kd + r0 + cc] = f2bf(Lt[cc][rr]);
  }
}

// ---------------------------------------------------------------------------
// V region of qkv [8192][2304] -> VT [bh=64][d=96][t=1024] bf16
// ---------------------------------------------------------------------------
__global__ __launch_bounds__(256) void v_transpose_kernel(
    const unsigned short* __restrict__ qkv, unsigned short* __restrict__ vt) {
  const int tid = threadIdx.x;
  const int token = blockIdx.x * 64 + (tid & 63);
  const int c = blockIdx.y * 4 + (tid >> 6);     // 0..95
  const int b = token >> 10, t = token & 1023;
  const int h = c / 12, cd = c % 12;
  const unsigned short* src =
      qkv + (size_t)token * N1_ + 2 * C_ + h * D_ + cd * 8;
  ushort4 a = *(const ushort4*)src;
  ushort4 b4 = *(const ushort4*)(src + 4);
  unsigned short v[8] = {a.x, a.y, a.z, a.w, b4.x, b4.y, b4.z, b4.w};
  size_t base = ((size_t)(b * H_ + h) * D_ + cd * 8) * T_ + t;
#pragma unroll
  for (int i = 0; i < 8; ++i) vt[base + (size_t)i * T_] = v[i];
}

// ---------------------------------------------------------------------------
// bf16 MFMA GEMM, register-staged pipeline:
//   regs(k+1) loaded during compute(k); ds_write after barrier1; barrier2;
//   MFMA. vmcnt wait lands at next iter's ds_write -> HBM latency hidden.
// Tile: (WM*32) x 128, BK=64. WM=4 -> 128x128 (qkv), WM=2 -> 64x128 (proj).
// LDS fragment order: slab s (16 rows), chunk c (32 K): lane l holds
// [s*16+(l&15)][c*32+(l>>4)*8 ..+7].
// ---------------------------------------------------------------------------
template <int WM, bool OUTF32>
__global__ __launch_bounds__(256) void gemm_mfma_kernel(
    const unsigned short* __restrict__ A, const unsigned short* __restrict__ Bt,
    const float* __restrict__ bias, void* __restrict__ Cout, int N, int K,
    int sc_lim, float sc) {
  constexpr int AS = 2 * WM;     // A slabs of 16 rows
  constexpr int PA = WM / 2;     // A slabs staged per wave
  __shared__ __align__(16) unsigned short As[AS * 1024];
  __shared__ __align__(16) unsigned short Bs[8 * 1024];
  const int tid = threadIdx.x;
  const int w = tid >> 6, l = tid & 63;
  const int lm = l & 15, lq = l >> 4;
  const int m0 = blockIdx.y * (AS * 16), n0 = blockIdx.x * 128;
  const int wrb = (w >> 1) * WM;
  const int wnb = (w & 1) * 4;

  f32x4 acc[WM][4];
#pragma unroll
  for (int i = 0; i < WM; ++i)
#pragma unroll
    for (int j = 0; j < 4; ++j) acc[i][j] = (f32x4){0.f, 0.f, 0.f, 0.f};

  const unsigned short* gA[PA][2];
  const unsigned short* gB[2][2];
#pragma unroll
  for (int s = 0; s < PA; ++s)
#pragma unroll
    for (int c = 0; c < 2; ++c)
      gA[s][c] = A + (size_t)(m0 + (w * PA + s) * 16 + lm) * K + c * 32 + lq * 8;
#pragma unroll
  for (int s = 0; s < 2; ++s)
#pragma unroll
    for (int c = 0; c < 2; ++c)
      gB[s][c] = Bt + (size_t)(n0 + (2 * w + s) * 16 + lm) * K + c * 32 + lq * 8;

  uint4 rA[PA][2], rB[2][2];
#pragma unroll
  for (int s = 0; s < PA; ++s)
#pragma unroll
    for (int c = 0; c < 2; ++c) { rA[s][c] = *(const uint4*)gA[s][c]; gA[s][c] += 64; }
#pragma unroll
  for (int s = 0; s < 2; ++s)
#pragma unroll
    for (int c = 0; c < 2; ++c) { rB[s][c] = *(const uint4*)gB[s][c]; gB[s][c] += 64; }

  for (int k0 = 0; k0 < K; k0 += 64) {
    __syncthreads();  // everyone done reading prev tile
#pragma unroll
    for (int s = 0; s < PA; ++s)
#pragma unroll
      for (int c = 0; c < 2; ++c)
        *(uint4*)&As[(w * PA + s) * 1024 + c * 512 + l * 8] = rA[s][c];
#pragma unroll
    for (int s = 0; s < 2; ++s)
#pragma unroll
      for (int c = 0; c < 2; ++c)
        *(uint4*)&Bs[(2 * w + s) * 1024 + c * 512 + l * 8] = rB[s][c];
    __syncthreads();  // tile visible
    if (k0 + 64 < K) {  // issue next-tile loads; consumed next iteration
#pragma unroll
      for (int s = 0; s < PA; ++s)
#pragma unroll
        for (int c = 0; c < 2; ++c) { rA[s][c] = *(const uint4*)gA[s][c]; gA[s][c] += 64; }
#pragma unroll
      for (int s = 0; s < 2; ++s)
#pragma unroll
        for (int c = 0; c < 2; ++c) { rB[s][c] = *(const uint4*)gB[s][c]; gB[s][c] += 64; }
    }
#pragma unroll
    for (int kk = 0; kk < 2; ++kk) {
      bf16x8 af[WM], bfr[4];
#pragma unroll
      for (int mi = 0; mi < WM; ++mi)
        af[mi] = *(const bf16x8*)&As[(wrb + mi) * 1024 + kk * 512 + l * 8];
#pragma unroll
      for (int ni = 0; ni < 4; ++ni)
        bfr[ni] = *(const bf16x8*)&Bs[(wnb + ni) * 1024 + kk * 512 + l * 8];
#pragma unroll
      for (int mi = 0; mi < WM; ++mi)
#pragma unroll
        for (int ni = 0; ni < 4; ++ni)
          acc[mi][ni] = __builtin_amdgcn_mfma_f32_16x16x32_bf16(
              af[mi], bfr[ni], acc[mi][ni], 0, 0, 0);
    }
  }

#pragma unroll
  for (int mi = 0; mi < WM; ++mi) {
    const int row = m0 + (wrb + mi) * 16 + lq * 4;
#pragma unroll
    for (int ni = 0; ni < 4; ++ni) {
      const int col = n0 + (wnb + ni) * 16 + lm;
      const float bv = bias[col];
      const float mul = (col < sc_lim) ? sc : 1.f;
#pragma unroll
      for (int r = 0; r < 4; ++r) {
        float v = (acc[mi][ni][r] + bv) * mul;
        if (OUTF32)
          ((float*)Cout)[(size_t)(row + r) * N + col] = v;
        else
          ((unsigned short*)Cout)[(size_t)(row + r) * N + col] = f2bf(v);
      }
    }
  }
}

// ---------------------------------------------------------------------------
// Flash causal attention, bf16 MFMA, max-free softmax (Q pre-scaled), l via
// ones-MFMA. Block = paired q-tiles (qt, 15-qt) x (b,h): 17 key-tiles each.
// K/V staging register-pipelined like the GEMM.
// ---------------------------------------------------------------------------
__global__ __launch_bounds__(256) void attn_mfma_kernel(
    const unsigned short* __restrict__ qkv,  // [8192][2304], Q pre-scaled
    const unsigned short* __restrict__ vt,   // [64][96][1024]
    unsigned short* __restrict__ y) {        // [8192][768]
  __shared__ __align__(16) unsigned short Ks[12 * 512];  // ck = kc*4+nb
  __shared__ __align__(16) unsigned short Vs[12 * 512];  // cv = db*2+vc
  __shared__ __align__(16) unsigned short Pt[4][16][72]; // pad 64->72

  const int tid = threadIdx.x;
  const int w = tid >> 6, l = tid & 63;
  const int lm = l & 15, lq = l >> 4;
  const int pi = blockIdx.x, bh = blockIdx.y;
  const int b = bh >> 3, h = bh & 7;
  const size_t bT = (size_t)b * T_;

  bf16x8 onef;
#pragma unroll
  for (int i = 0; i < 8; ++i) onef[i] = (__bf16)1.0f;

  uint4 rT[6];
  auto issue = [&](int j0) {
#pragma unroll
    for (int i = 0; i < 6; ++i) {
      const int c = w * 6 + i;
      const unsigned short* g;
      if (c < 12) {  // K chunk (B-frag for QK^T)
        const int kc = c >> 2, nb = c & 3;
        g = qkv + (bT + j0 + nb * 16 + lm) * N1_ + C_ + h * D_ + kc * 32 + lq * 8;
      } else {       // V chunk (B-frag for PV, from VT)
        const int cv = c - 12;
        const int db = cv >> 1, vc = cv & 1;
        g = vt + ((size_t)bh * D_ + db * 16 + lm) * T_ + j0 + vc * 32 + lq * 8;
      }
      rT[i] = *(const uint4*)g;
    }
  };

  for (int half = 0; half < 2; ++half) {
    const int qt = half ? (15 - pi) : pi;
    const int q0 = qt * 64;

    bf16x8 qf[3];
    {
      const unsigned short* qp =
          qkv + (bT + q0 + w * 16 + lm) * N1_ + h * D_ + lq * 8;
      qf[0] = *(const bf16x8*)(qp);
      qf[1] = *(const bf16x8*)(qp + 32);
      qf[2] = *(const bf16x8*)(qp + 64);
    }
    f32x4 o[7];  // 6 dim-blocks + l accumulator
#pragma unroll
    for (int i = 0; i < 7; ++i) o[i] = (f32x4){0.f, 0.f, 0.f, 0.f};

    issue(0);
    for (int jt = 0; jt <= qt; ++jt) {
      __syncthreads();  // prior tile's LDS fully consumed
#pragma unroll
      for (int i = 0; i < 6; ++i) {
        const int c = w * 6 + i;
        unsigned short* dst = (c < 12) ? &Ks[c * 512] : &Vs[(c - 12) * 512];
        *(uint4*)&dst[l * 8] = rT[i];
      }
      __syncthreads();
      if (jt < qt) issue((jt + 1) * 64);

      const bool diag = (jt == qt);
#pragma unroll
      for (int nb = 0; nb < 4; ++nb) {
        if (diag && nb > w) {  // wave-uniform: block fully masked
#pragma unroll
          for (int r = 0; r < 4; ++r)
            Pt[w][lq * 4 + r][nb * 16 + lm] = 0;
          continue;
        }
        f32x4 a = (f32x4){0.f, 0.f, 0.f, 0.f};
#pragma unroll
        for (int kc = 0; kc < 3; ++kc) {
          bf16x8 kf = *(const bf16x8*)&Ks[(kc * 4 + nb) * 512 + l * 8];
          a = __builtin_amdgcn_mfma_f32_16x16x32_bf16(qf[kc], kf, a, 0, 0, 0);
        }
#pragma unroll
        for (int r = 0; r < 4; ++r) {
          float s = a[r];
          if (diag && (nb * 16 + lm > w * 16 + lq * 4 + r)) s = -INFINITY;
          Pt[w][lq * 4 + r][nb * 16 + lm] = f2bf(__expf(s));
        }
      }

      // PV: P as A-frag (per-wave LDS round trip), V-frags + ones-frag
      bf16x8 pf0 = *(const bf16x8*)&Pt[w][lm][lq * 8];
      bf16x8 pf1 = *(const bf16x8*)&Pt[w][lm][32 + lq * 8];
#pragma unroll
      for (int db = 0; db < 6; ++db) {
        bf16x8 vf0 = *(const bf16x8*)&Vs[(db * 2 + 0) * 512 + l * 8];
        bf16x8 vf1 = *(const bf16x8*)&Vs[(db * 2 + 1) * 512 + l * 8];
        o[db] = __builtin_amdgcn_mfma_f32_16x16x32_bf16(pf0, vf0, o[db], 0, 0, 0);
        o[db] = __builtin_amdgcn_mfma_f32_16x16x32_bf16(pf1, vf1, o[db], 0, 0, 0);
      }
      o[6] = __builtin_amdgcn_mfma_f32_16x16x32_bf16(pf0, onef, o[6], 0, 0, 0);
      o[6] = __builtin_amdgcn_mfma_f32_16x16x32_bf16(pf1, onef, o[6], 0, 0, 0);
    }

#pragma unroll
    for (int r = 0; r < 4; ++r) {
      const float inv = 1.f / o[6][r];
      const size_t row = bT + q0 + w * 16 + lq * 4 + r;
#pragma unroll
      for (int db = 0; db < 6; ++db)
        y[row * C_ + h * D_ + db * 16 + lm] = f2bf(o[db][r] * inv);
    }
  }
}

// ---------------------------------------------------------------------------
extern "C" void kernel_launch(void* const* d_in, const int* in_sizes, int n_in,
                              void* d_out, int out_size, void* d_ws, size_t ws_size,
                              hipStream_t stream) {
  const float* x      = (const float*)d_in[0];
  const float* W_attn = (const float*)d_in[1];
  const float* b_attn = (const float*)d_in[2];
  const float* W_proj = (const float*)d_in[3];
  const float* b_proj = (const float*)d_in[4];
  float* out = (float*)d_out;

  char* ws = (char*)d_ws;
  unsigned short* xb  = (unsigned short*)(ws);                    // 12.58 MB
  unsigned short* WaT = (unsigned short*)(ws + 12582912);         //  3.54 MB
  unsigned short* WpT = (unsigned short*)(ws + 16121856);         //  1.18 MB
  unsigned short* qkv = (unsigned short*)(ws + 17301504);         // 37.75 MB
  unsigned short* vt  = (unsigned short*)(ws + 55050240);         // 12.58 MB
  unsigned short* yb  = (unsigned short*)(ws + 67633152);         // 12.58 MB

  const float qscale = 0.10206207261596577f;  // 1/sqrt(96)

  cvt_bf16_kernel<<<(M_ * C_) / 1024, 256, 0, stream>>>(x, xb, M_ * C_);
  w_transpose_kernel<<<dim3(C_ / 32, N1_ / 32), 256, 0, stream>>>(W_attn, WaT, C_, N1_);
  w_transpose_kernel<<<dim3(C_ / 32, C_ / 32), 256, 0, stream>>>(W_proj, WpT, C_, C_);

  // qkv = x @ W_attn + b_attn; Q columns (<768) pre-scaled by 1/sqrt(D) in fp32
  gemm_mfma_kernel<4, false><<<dim3(N1_ / 128, M_ / 128), 256, 0, stream>>>(
      xb, WaT, b_attn, qkv, N1_, C_, C_, qscale);
  v_transpose_kernel<<<dim3(M_ / 64, 24), 256, 0, stream>>>(qkv, vt);
  attn_mfma_kernel<<<dim3(8, B_ * H_), 256, 0, stream>>>(qkv, vt, yb);
  // proj: 64x128 tiles -> 768 blocks (3/CU) for better balance
  gemm_mfma_kernel<2, true><<<dim3(C_ / 128, M_ / 64), 256, 0, stream>>>(
      yb, WpT, b_proj, out, C_, C_, 0, 1.f);
}

// Round 5
// 234.733 us; speedup vs baseline: 1.7886x; 1.7886x over previous
//
#include <hip/hip_runtime.h>
#include <math.h>

#define B_ 8
#define T_ 1024
#define C_ 768
#define H_ 8
#define D_ 96
#define M_ (B_ * T_)     // 8192 tokens
#define N1_ (3 * C_)     // 2304

typedef __bf16 bf16x8 __attribute__((ext_vector_type(8)));
typedef float f32x4 __attribute__((ext_vector_type(4)));

__device__ __forceinline__ unsigned short f2bf(float f) {
  unsigned int u = __float_as_uint(f);
  u += 0x7FFF + ((u >> 16) & 1);          // round-to-nearest-even
  return (unsigned short)(u >> 16);
}

// async global->LDS, 16B per lane; LDS dest = uniform base + lane*16
__device__ __forceinline__ void load_lds16(const void* g, void* l) {
  __builtin_amdgcn_global_load_lds(
      (const __attribute__((address_space(1))) unsigned int*)g,
      (__attribute__((address_space(3))) unsigned int*)l, 16, 0, 0);
}

// ---------------------------------------------------------------------------
// fp32 -> bf16 elementwise (for x)
// ---------------------------------------------------------------------------
__global__ __launch_bounds__(256) void cvt_bf16_kernel(
    const float* __restrict__ in, unsigned short* __restrict__ out, int n) {
  int i = (blockIdx.x * 256 + threadIdx.x) * 4;
  if (i + 3 < n) {
    float4 v = *(const float4*)(in + i);
    ushort4 o;
    o.x = f2bf(v.x); o.y = f2bf(v.y); o.z = f2bf(v.z); o.w = f2bf(v.w);
    *(ushort4*)(out + i) = o;
  }
}

// ---------------------------------------------------------------------------
// W [Kd][Nd] fp32 -> WT [Nd][Kd] bf16
// ---------------------------------------------------------------------------
__global__ __launch_bounds__(256) void w_transpose_kernel(
    const float* __restrict__ W, unsigned short* __restrict__ WT,
    int Kd, int Nd) {
  __shared__ float Lt[32][33];
  const int r0 = blockIdx.x * 32;   // Kd
  const int c0 = blockIdx.y * 32;   // Nd
#pragma unroll
  for (int i = 0; i < 4; ++i) {
    int e = threadIdx.x + 256 * i;
    int r = e >> 5, c = e & 31;
    Lt[r][c] = W[(size_t)(r0 + r) * Nd + c0 + c];
  }
  __syncthreads();
#pragma unroll
  for (int i = 0; i < 4; ++i) {
    int e = threadIdx.x + 256 * i;
    int rr = e >> 5, cc = e & 31;
    WT[(size_t)(c0 + rr) * Kd + r0 + cc] = f2bf(Lt[cc][rr]);
  }
}

// ---------------------------------------------------------------------------
// V region of qkv [8192][2304] -> VT [bh=64][d=96][t=1024] bf16
// ---------------------------------------------------------------------------
__global__ __launch_bounds__(256) void v_transpose_kernel(
    const unsigned short* __restrict__ qkv, unsigned short* __restrict__ vt) {
  const int tid = threadIdx.x;
  const int token = blockIdx.x * 64 + (tid & 63);
  const int c = blockIdx.y * 4 + (tid >> 6);     // 0..95
  const int b = token >> 10, t = token & 1023;
  const int h = c / 12, cd = c % 12;
  const unsigned short* src =
      qkv + (size_t)token * N1_ + 2 * C_ + h * D_ + cd * 8;
  ushort4 a = *(const ushort4*)src;
  ushort4 b4 = *(const ushort4*)(src + 4);
  unsigned short v[8] = {a.x, a.y, a.z, a.w, b4.x, b4.y, b4.z, b4.w};
  size_t base = ((size_t)(b * H_ + h) * D_ + cd * 8) * T_ + t;
#pragma unroll
  for (int i = 0; i < 8; ++i) vt[base + (size_t)i * T_] = v[i];
}

// ---------------------------------------------------------------------------
// bf16 MFMA GEMM with double-buffered LDS, BK=32, global_load_lds staging.
// Per iter: barrier (drains prefetch issued one compute-phase ago) ->
// issue next tile into buf^1 -> ds_read frags + MFMA from buf.
// Tile: (2*WM*16) x 128. WM=4 -> 128x128, WM=2 -> 64x128.
// Chunk c (512 shorts = 16 rows x 32 k, fragment order): c<AS A slab, else B.
// ---------------------------------------------------------------------------
template <int WM, bool OUTF32>
__global__ __launch_bounds__(256) void gemm_mfma_kernel(
    const unsigned short* __restrict__ A, const unsigned short* __restrict__ Bt,
    const float* __restrict__ bias, void* __restrict__ Cout, int N, int K,
    int sc_lim, float sc) {
  constexpr int AS  = 2 * WM;      // A slabs of 16 rows
  constexpr int NC  = AS + 8;      // chunks per buffer
  constexpr int CPW = NC / 4;      // chunks staged per wave
  __shared__ __align__(16) unsigned short Sb[2][NC * 512];
  const int tid = threadIdx.x;
  const int w = tid >> 6, l = tid & 63;
  const int lm = l & 15, lq = l >> 4;
  const int m0 = blockIdx.y * (AS * 16), n0 = blockIdx.x * 128;
  const int wrb = (w >> 1) * WM;   // wave A-slab base
  const int wnb = (w & 1) * 4;     // wave B-slab base

  f32x4 acc[WM][4];
#pragma unroll
  for (int i = 0; i < WM; ++i)
#pragma unroll
    for (int j = 0; j < 4; ++j) acc[i][j] = (f32x4){0.f, 0.f, 0.f, 0.f};

  const unsigned short* gp[CPW];
#pragma unroll
  for (int i = 0; i < CPW; ++i) {
    const int c = w * CPW + i;
    gp[i] = (c < AS)
        ? A  + (size_t)(m0 + c * 16 + lm) * K + lq * 8
        : Bt + (size_t)(n0 + (c - AS) * 16 + lm) * K + lq * 8;
  }

  // prologue: stage k0=0 into buffer 0
#pragma unroll
  for (int i = 0; i < CPW; ++i) {
    load_lds16(gp[i], &Sb[0][(w * CPW + i) * 512]);
    gp[i] += 32;
  }

  int cur = 0;
  for (int k0 = 0; k0 < K; k0 += 32) {
    __syncthreads();  // vmcnt(0): buf[cur] ready; prev compute done
    if (k0 + 32 < K) {
#pragma unroll
      for (int i = 0; i < CPW; ++i) {
        load_lds16(gp[i], &Sb[cur ^ 1][(w * CPW + i) * 512]);
        gp[i] += 32;
      }
    }
    bf16x8 af[WM], bfr[4];
#pragma unroll
    for (int mi = 0; mi < WM; ++mi)
      af[mi] = *(const bf16x8*)&Sb[cur][(wrb + mi) * 512 + l * 8];
#pragma unroll
    for (int ni = 0; ni < 4; ++ni)
      bfr[ni] = *(const bf16x8*)&Sb[cur][(AS + wnb + ni) * 512 + l * 8];
#pragma unroll
    for (int mi = 0; mi < WM; ++mi)
#pragma unroll
      for (int ni = 0; ni < 4; ++ni)
        acc[mi][ni] = __builtin_amdgcn_mfma_f32_16x16x32_bf16(
            af[mi], bfr[ni], acc[mi][ni], 0, 0, 0);
    cur ^= 1;
  }

#pragma unroll
  for (int mi = 0; mi < WM; ++mi) {
    const int row = m0 + (wrb + mi) * 16 + lq * 4;
#pragma unroll
    for (int ni = 0; ni < 4; ++ni) {
      const int col = n0 + (wnb + ni) * 16 + lm;
      const float bv = bias[col];
      const float mul = (col < sc_lim) ? sc : 1.f;
#pragma unroll
      for (int r = 0; r < 4; ++r) {
        float v = (acc[mi][ni][r] + bv) * mul;
        if (OUTF32)
          ((float*)Cout)[(size_t)(row + r) * N + col] = v;
        else
          ((unsigned short*)Cout)[(size_t)(row + r) * N + col] = f2bf(v);
      }
    }
  }
}

// ---------------------------------------------------------------------------
// Flash causal attention, bf16 MFMA, max-free softmax (Q pre-scaled), l via
// ones-MFMA, paired q-tiles (qt, 15-pi): 17 key-tiles per block.
// K/V double-buffered in LDS via global_load_lds, one barrier per key-tile.
// ---------------------------------------------------------------------------
__global__ __launch_bounds__(256) void attn_mfma_kernel(
    const unsigned short* __restrict__ qkv,  // [8192][2304], Q pre-scaled
    const unsigned short* __restrict__ vt,   // [64][96][1024]
    unsigned short* __restrict__ y) {        // [8192][768]
  // chunk c<12: K (ck = kc*4+nb); c>=12: V (cv = db*2+vc)
  __shared__ __align__(16) unsigned short KV[2][24 * 512];  // 48 KB
  __shared__ __align__(16) unsigned short Pt[4][16][72];    // pad 64->72

  const int tid = threadIdx.x;
  const int w = tid >> 6, l = tid & 63;
  const int lm = l & 15, lq = l >> 4;
  const int pi = blockIdx.x, bh = blockIdx.y;
  const int b = bh >> 3, h = bh & 7;
  const size_t bT = (size_t)b * T_;

  bf16x8 onef;
#pragma unroll
  for (int i = 0; i < 8; ++i) onef[i] = (__bf16)1.0f;

  auto issue = [&](int j0, int buf) {
#pragma unroll
    for (int i = 0; i < 6; ++i) {
      const int c = w * 6 + i;
      const unsigned short* g;
      if (c < 12) {  // K chunk (B-frag for QK^T)
        const int kc = c >> 2, nb = c & 3;
        g = qkv + (bT + j0 + nb * 16 + lm) * N1_ + C_ + h * D_ + kc * 32 + lq * 8;
      } else {       // V chunk (B-frag for PV, from VT)
        const int cv = c - 12;
        const int db = cv >> 1, vc = cv & 1;
        g = vt + ((size_t)bh * D_ + db * 16 + lm) * T_ + j0 + vc * 32 + lq * 8;
      }
      load_lds16(g, &KV[buf][c * 512]);
    }
  };

  int cur = 0;
  issue(0, 0);  // prologue: first key-tile of first half

  for (int half = 0; half < 2; ++half) {
    const int qt = half ? (15 - pi) : pi;
    const int q0 = qt * 64;

    bf16x8 qf[3];
    {
      const unsigned short* qp =
          qkv + (bT + q0 + w * 16 + lm) * N1_ + h * D_ + lq * 8;
      qf[0] = *(const bf16x8*)(qp);
      qf[1] = *(const bf16x8*)(qp + 32);
      qf[2] = *(const bf16x8*)(qp + 64);
    }
    f32x4 o[7];  // 6 dim-blocks + l accumulator
#pragma unroll
    for (int i = 0; i < 7; ++i) o[i] = (f32x4){0.f, 0.f, 0.f, 0.f};

    for (int jt = 0; jt <= qt; ++jt) {
      __syncthreads();  // vmcnt(0): KV[cur] ready; prev tile's reads done
      if (jt < qt)          issue((jt + 1) * 64, cur ^ 1);
      else if (half == 0)   issue(0, cur ^ 1);  // first tile of second half

      const bool diag = (jt == qt);
#pragma unroll
      for (int nb = 0; nb < 4; ++nb) {
        if (diag && nb > w) {  // wave-uniform: block fully masked
#pragma unroll
          for (int r = 0; r < 4; ++r)
            Pt[w][lq * 4 + r][nb * 16 + lm] = 0;
          continue;
        }
        f32x4 a = (f32x4){0.f, 0.f, 0.f, 0.f};
#pragma unroll
        for (int kc = 0; kc < 3; ++kc) {
          bf16x8 kf = *(const bf16x8*)&KV[cur][(kc * 4 + nb) * 512 + l * 8];
          a = __builtin_amdgcn_mfma_f32_16x16x32_bf16(qf[kc], kf, a, 0, 0, 0);
        }
#pragma unroll
        for (int r = 0; r < 4; ++r) {
          float s = a[r];
          if (diag && (nb * 16 + lm > w * 16 + lq * 4 + r)) s = -INFINITY;
          Pt[w][lq * 4 + r][nb * 16 + lm] = f2bf(__expf(s));
        }
      }

      // PV: P as A-frag (per-wave LDS round trip), V-frags + ones-frag
      bf16x8 pf0 = *(const bf16x8*)&Pt[w][lm][lq * 8];
      bf16x8 pf1 = *(const bf16x8*)&Pt[w][lm][32 + lq * 8];
#pragma unroll
      for (int db = 0; db < 6; ++db) {
        bf16x8 vf0 = *(const bf16x8*)&KV[cur][(12 + db * 2 + 0) * 512 + l * 8];
        bf16x8 vf1 = *(const bf16x8*)&KV[cur][(12 + db * 2 + 1) * 512 + l * 8];
        o[db] = __builtin_amdgcn_mfma_f32_16x16x32_bf16(pf0, vf0, o[db], 0, 0, 0);
        o[db] = __builtin_amdgcn_mfma_f32_16x16x32_bf16(pf1, vf1, o[db], 0, 0, 0);
      }
      o[6] = __builtin_amdgcn_mfma_f32_16x16x32_bf16(pf0, onef, o[6], 0, 0, 0);
      o[6] = __builtin_amdgcn_mfma_f32_16x16x32_bf16(pf1, onef, o[6], 0, 0, 0);
      cur ^= 1;
    }

#pragma unroll
    for (int r = 0; r < 4; ++r) {
      const float inv = 1.f / o[6][r];
      const size_t row = bT + q0 + w * 16 + lq * 4 + r;
#pragma unroll
      for (int db = 0; db < 6; ++db)
        y[row * C_ + h * D_ + db * 16 + lm] = f2bf(o[db][r] * inv);
    }
  }
}

// ---------------------------------------------------------------------------
extern "C" void kernel_launch(void* const* d_in, const int* in_sizes, int n_in,
                              void* d_out, int out_size, void* d_ws, size_t ws_size,
                              hipStream_t stream) {
  const float* x      = (const float*)d_in[0];
  const float* W_attn = (const float*)d_in[1];
  const float* b_attn = (const float*)d_in[2];
  const float* W_proj = (const float*)d_in[3];
  const float* b_proj = (const float*)d_in[4];
  float* out = (float*)d_out;

  char* ws = (char*)d_ws;
  unsigned short* xb  = (unsigned short*)(ws);                    // 12.58 MB
  unsigned short* WaT = (unsigned short*)(ws + 12582912);         //  3.54 MB
  unsigned short* WpT = (unsigned short*)(ws + 16121856);         //  1.18 MB
  unsigned short* qkv = (unsigned short*)(ws + 17301504);         // 37.75 MB
  unsigned short* vt  = (unsigned short*)(ws + 55050240);         // 12.58 MB
  unsigned short* yb  = (unsigned short*)(ws + 67633152);         // 12.58 MB

  const float qscale = 0.10206207261596577f;  // 1/sqrt(96)

  cvt_bf16_kernel<<<(M_ * C_) / 1024, 256, 0, stream>>>(x, xb, M_ * C_);
  w_transpose_kernel<<<dim3(C_ / 32, N1_ / 32), 256, 0, stream>>>(W_attn, WaT, C_, N1_);
  w_transpose_kernel<<<dim3(C_ / 32, C_ / 32), 256, 0, stream>>>(W_proj, WpT, C_, C_);

  // qkv = x @ W_attn + b_attn; Q columns (<768) pre-scaled by 1/sqrt(D) in fp32
  gemm_mfma_kernel<4, false><<<dim3(N1_ / 128, M_ / 128), 256, 0, stream>>>(
      xb, WaT, b_attn, qkv, N1_, C_, C_, qscale);
  v_transpose_kernel<<<dim3(M_ / 64, 24), 256, 0, stream>>>(qkv, vt);
  attn_mfma_kernel<<<dim3(8, B_ * H_), 256, 0, stream>>>(qkv, vt, yb);
  // proj: 64x128 tiles -> 768 blocks (3/CU)
  gemm_mfma_kernel<2, true><<<dim3(C_ / 128, M_ / 64), 256, 0, stream>>>(
      yb, WpT, b_proj, out, C_, C_, 0, 1.f);
}

// Round 6
// 229.083 us; speedup vs baseline: 1.8327x; 1.0247x over previous
//
#include <hip/hip_runtime.h>
#include <math.h>

#define B_ 8
#define T_ 1024
#define C_ 768
#define H_ 8
#define D_ 96
#define M_ (B_ * T_)     // 8192 tokens
#define N1_ (3 * C_)     // 2304

typedef __bf16 bf16x8 __attribute__((ext_vector_type(8)));
typedef float f32x4 __attribute__((ext_vector_type(4)));

__device__ __forceinline__ unsigned short f2bf(float f) {
  unsigned int u = __float_as_uint(f);
  u += 0x7FFF + ((u >> 16) & 1);          // round-to-nearest-even
  return (unsigned short)(u >> 16);
}

// async global->LDS, 16B per lane; LDS dest = uniform base + lane*16
__device__ __forceinline__ void load_lds16(const void* g, void* l) {
  __builtin_amdgcn_global_load_lds(
      (const __attribute__((address_space(1))) unsigned int*)g,
      (__attribute__((address_space(3))) unsigned int*)l, 16, 0, 0);
}

// ---------------------------------------------------------------------------
// fp32 -> bf16 elementwise (for x)
// ---------------------------------------------------------------------------
__global__ __launch_bounds__(256) void cvt_bf16_kernel(
    const float* __restrict__ in, unsigned short* __restrict__ out, int n) {
  int i = (blockIdx.x * 256 + threadIdx.x) * 4;
  if (i + 3 < n) {
    float4 v = *(const float4*)(in + i);
    ushort4 o;
    o.x = f2bf(v.x); o.y = f2bf(v.y); o.z = f2bf(v.z); o.w = f2bf(v.w);
    *(ushort4*)(out + i) = o;
  }
}

// ---------------------------------------------------------------------------
// W [Kd][Nd] fp32 -> WT [Nd][Kd] bf16
// ---------------------------------------------------------------------------
__global__ __launch_bounds__(256) void w_transpose_kernel(
    const float* __restrict__ W, unsigned short* __restrict__ WT,
    int Kd, int Nd) {
  __shared__ float Lt[32][33];
  const int r0 = blockIdx.x * 32;   // Kd
  const int c0 = blockIdx.y * 32;   // Nd
#pragma unroll
  for (int i = 0; i < 4; ++i) {
    int e = threadIdx.x + 256 * i;
    int r = e >> 5, c = e & 31;
    Lt[r][c] = W[(size_t)(r0 + r) * Nd + c0 + c];
  }
  __syncthreads();
#pragma unroll
  for (int i = 0; i < 4; ++i) {
    int e = threadIdx.x + 256 * i;
    int rr = e >> 5, cc = e & 31;
    WT[(size_t)(c0 + rr) * Kd + r0 + cc] = f2bf(Lt[cc][rr]);
  }
}

// ---------------------------------------------------------------------------
// V region of qkv [8192][2304] -> VT [bh=64][d=96][t=1024] bf16
// ---------------------------------------------------------------------------
__global__ __launch_bounds__(256) void v_transpose_kernel(
    const unsigned short* __restrict__ qkv, unsigned short* __restrict__ vt) {
  const int tid = threadIdx.x;
  const int token = blockIdx.x * 64 + (tid & 63);
  const int c = blockIdx.y * 4 + (tid >> 6);     // 0..95
  const int b = token >> 10, t = token & 1023;
  const int h = c / 12, cd = c % 12;
  const unsigned short* src =
      qkv + (size_t)token * N1_ + 2 * C_ + h * D_ + cd * 8;
  ushort4 a = *(const ushort4*)src;
  ushort4 b4 = *(const ushort4*)(src + 4);
  unsigned short v[8] = {a.x, a.y, a.z, a.w, b4.x, b4.y, b4.z, b4.w};
  size_t base = ((size_t)(b * H_ + h) * D_ + cd * 8) * T_ + t;
#pragma unroll
  for (int i = 0; i < 8; ++i) vt[base + (size_t)i * T_] = v[i];
}

// ---------------------------------------------------------------------------
// bf16 MFMA GEMM with double-buffered LDS, BK=32, global_load_lds staging.
// 1-D grid, XCD-locality swizzle: bm = id & mmask (pow2 M-panels) so all
// N-blocks of one M-panel share id mod 8 -> same XCD -> A-panel L2-resident.
// Tile: (2*WM*16) x 128. WM=4 -> 128x128, WM=2 -> 64x128.
// ---------------------------------------------------------------------------
template <int WM, bool OUTF32>
__global__ __launch_bounds__(256) void gemm_mfma_kernel(
    const unsigned short* __restrict__ A, const unsigned short* __restrict__ Bt,
    const float* __restrict__ bias, void* __restrict__ Cout, int N, int K,
    int sc_lim, float sc, int mmask, int mshift) {
  constexpr int AS  = 2 * WM;      // A slabs of 16 rows
  constexpr int NC  = AS + 8;      // chunks per buffer
  constexpr int CPW = NC / 4;      // chunks staged per wave
  __shared__ __align__(16) unsigned short Sb[2][NC * 512];
  const int tid = threadIdx.x;
  const int w = tid >> 6, l = tid & 63;
  const int lm = l & 15, lq = l >> 4;
  const int bid = blockIdx.x;
  const int m0 = (bid & mmask) * (AS * 16), n0 = (bid >> mshift) * 128;
  const int wrb = (w >> 1) * WM;   // wave A-slab base
  const int wnb = (w & 1) * 4;     // wave B-slab base

  f32x4 acc[WM][4];
#pragma unroll
  for (int i = 0; i < WM; ++i)
#pragma unroll
    for (int j = 0; j < 4; ++j) acc[i][j] = (f32x4){0.f, 0.f, 0.f, 0.f};

  const unsigned short* gp[CPW];
#pragma unroll
  for (int i = 0; i < CPW; ++i) {
    const int c = w * CPW + i;
    gp[i] = (c < AS)
        ? A  + (size_t)(m0 + c * 16 + lm) * K + lq * 8
        : Bt + (size_t)(n0 + (c - AS) * 16 + lm) * K + lq * 8;
  }

  // prologue: stage k0=0 into buffer 0
#pragma unroll
  for (int i = 0; i < CPW; ++i) {
    load_lds16(gp[i], &Sb[0][(w * CPW + i) * 512]);
    gp[i] += 32;
  }

  int cur = 0;
  for (int k0 = 0; k0 < K; k0 += 32) {
    __syncthreads();  // vmcnt(0): buf[cur] ready; prev compute done
    if (k0 + 32 < K) {
#pragma unroll
      for (int i = 0; i < CPW; ++i) {
        load_lds16(gp[i], &Sb[cur ^ 1][(w * CPW + i) * 512]);
        gp[i] += 32;
      }
    }
    bf16x8 af[WM], bfr[4];
#pragma unroll
    for (int mi = 0; mi < WM; ++mi)
      af[mi] = *(const bf16x8*)&Sb[cur][(wrb + mi) * 512 + l * 8];
#pragma unroll
    for (int ni = 0; ni < 4; ++ni)
      bfr[ni] = *(const bf16x8*)&Sb[cur][(AS + wnb + ni) * 512 + l * 8];
#pragma unroll
    for (int mi = 0; mi < WM; ++mi)
#pragma unroll
      for (int ni = 0; ni < 4; ++ni)
        acc[mi][ni] = __builtin_amdgcn_mfma_f32_16x16x32_bf16(
            af[mi], bfr[ni], acc[mi][ni], 0, 0, 0);
    cur ^= 1;
  }

#pragma unroll
  for (int mi = 0; mi < WM; ++mi) {
    const int row = m0 + (wrb + mi) * 16 + lq * 4;
#pragma unroll
    for (int ni = 0; ni < 4; ++ni) {
      const int col = n0 + (wnb + ni) * 16 + lm;
      const float bv = bias[col];
      const float mul = (col < sc_lim) ? sc : 1.f;
#pragma unroll
      for (int r = 0; r < 4; ++r) {
        float v = (acc[mi][ni][r] + bv) * mul;
        if (OUTF32)
          ((float*)Cout)[(size_t)(row + r) * N + col] = v;
        else
          ((unsigned short*)Cout)[(size_t)(row + r) * N + col] = f2bf(v);
      }
    }
  }
}

// ---------------------------------------------------------------------------
// Flash causal attention, bf16 MFMA, max-free softmax (Q pre-scaled), l via
// ones-MFMA, paired q-tiles (qt, 15-pi): 17 key-tiles per block.
// 1-D grid, bh = id & 63: the 8 blocks of one (b,h) share an XCD -> K/V
// L2-resident (384 KB x 8 bh = 3 MB per XCD L2).
// ---------------------------------------------------------------------------
__global__ __launch_bounds__(256) void attn_mfma_kernel(
    const unsigned short* __restrict__ qkv,  // [8192][2304], Q pre-scaled
    const unsigned short* __restrict__ vt,   // [64][96][1024]
    unsigned short* __restrict__ y) {        // [8192][768]
  // chunk c<12: K (ck = kc*4+nb); c>=12: V (cv = db*2+vc)
  __shared__ __align__(16) unsigned short KV[2][24 * 512];  // 48 KB
  __shared__ __align__(16) unsigned short Pt[4][16][72];    // pad 64->72

  const int tid = threadIdx.x;
  const int w = tid >> 6, l = tid & 63;
  const int lm = l & 15, lq = l >> 4;
  const int bh = blockIdx.x & 63, pi = blockIdx.x >> 6;
  const int b = bh >> 3, h = bh & 7;
  const size_t bT = (size_t)b * T_;

  bf16x8 onef;
#pragma unroll
  for (int i = 0; i < 8; ++i) onef[i] = (__bf16)1.0f;

  auto issue = [&](int j0, int buf) {
#pragma unroll
    for (int i = 0; i < 6; ++i) {
      const int c = w * 6 + i;
      const unsigned short* g;
      if (c < 12) {  // K chunk (B-frag for QK^T)
        const int kc = c >> 2, nb = c & 3;
        g = qkv + (bT + j0 + nb * 16 + lm) * N1_ + C_ + h * D_ + kc * 32 + lq * 8;
      } else {       // V chunk (B-frag for PV, from VT)
        const int cv = c - 12;
        const int db = cv >> 1, vc = cv & 1;
        g = vt + ((size_t)bh * D_ + db * 16 + lm) * T_ + j0 + vc * 32 + lq * 8;
      }
      load_lds16(g, &KV[buf][c * 512]);
    }
  };

  int cur = 0;
  issue(0, 0);  // prologue: first key-tile of first half

  for (int half = 0; half < 2; ++half) {
    const int qt = half ? (15 - pi) : pi;
    const int q0 = qt * 64;

    bf16x8 qf[3];
    {
      const unsigned short* qp =
          qkv + (bT + q0 + w * 16 + lm) * N1_ + h * D_ + lq * 8;
      qf[0] = *(const bf16x8*)(qp);
      qf[1] = *(const bf16x8*)(qp + 32);
      qf[2] = *(const bf16x8*)(qp + 64);
    }
    f32x4 o[7];  // 6 dim-blocks + l accumulator
#pragma unroll
    for (int i = 0; i < 7; ++i) o[i] = (f32x4){0.f, 0.f, 0.f, 0.f};

    for (int jt = 0; jt <= qt; ++jt) {
      __syncthreads();  // vmcnt(0): KV[cur] ready; prev tile's reads done
      if (jt < qt)          issue((jt + 1) * 64, cur ^ 1);
      else if (half == 0)   issue(0, cur ^ 1);  // first tile of second half

      const bool diag = (jt == qt);
#pragma unroll
      for (int nb = 0; nb < 4; ++nb) {
        if (diag && nb > w) {  // wave-uniform: block fully masked
#pragma unroll
          for (int r = 0; r < 4; ++r)
            Pt[w][lq * 4 + r][nb * 16 + lm] = 0;
          continue;
        }
        f32x4 a = (f32x4){0.f, 0.f, 0.f, 0.f};
#pragma unroll
        for (int kc = 0; kc < 3; ++kc) {
          bf16x8 kf = *(const bf16x8*)&KV[cur][(kc * 4 + nb) * 512 + l * 8];
          a = __builtin_amdgcn_mfma_f32_16x16x32_bf16(qf[kc], kf, a, 0, 0, 0);
        }
#pragma unroll
        for (int r = 0; r < 4; ++r) {
          float s = a[r];
          if (diag && (nb * 16 + lm > w * 16 + lq * 4 + r)) s = -INFINITY;
          Pt[w][lq * 4 + r][nb * 16 + lm] = f2bf(__expf(s));
        }
      }

      // PV: P as A-frag (per-wave LDS round trip), V-frags + ones-frag
      bf16x8 pf0 = *(const bf16x8*)&Pt[w][lm][lq * 8];
      bf16x8 pf1 = *(const bf16x8*)&Pt[w][lm][32 + lq * 8];
#pragma unroll
      for (int db = 0; db < 6; ++db) {
        bf16x8 vf0 = *(const bf16x8*)&KV[cur][(12 + db * 2 + 0) * 512 + l * 8];
        bf16x8 vf1 = *(const bf16x8*)&KV[cur][(12 + db * 2 + 1) * 512 + l * 8];
        o[db] = __builtin_amdgcn_mfma_f32_16x16x32_bf16(pf0, vf0, o[db], 0, 0, 0);
        o[db] = __builtin_amdgcn_mfma_f32_16x16x32_bf16(pf1, vf1, o[db], 0, 0, 0);
      }
      o[6] = __builtin_amdgcn_mfma_f32_16x16x32_bf16(pf0, onef, o[6], 0, 0, 0);
      o[6] = __builtin_amdgcn_mfma_f32_16x16x32_bf16(pf1, onef, o[6], 0, 0, 0);
      cur ^= 1;
    }

#pragma unroll
    for (int r = 0; r < 4; ++r) {
      const float inv = 1.f / o[6][r];
      const size_t row = bT + q0 + w * 16 + lq * 4 + r;
#pragma unroll
      for (int db = 0; db < 6; ++db)
        y[row * C_ + h * D_ + db * 16 + lm] = f2bf(o[db][r] * inv);
    }
  }
}

// ---------------------------------------------------------------------------
extern "C" void kernel_launch(void* const* d_in, const int* in_sizes, int n_in,
                              void* d_out, int out_size, void* d_ws, size_t ws_size,
                              hipStream_t stream) {
  const float* x      = (const float*)d_in[0];
  const float* W_attn = (const float*)d_in[1];
  const float* b_attn = (const float*)d_in[2];
  const float* W_proj = (const float*)d_in[3];
  const float* b_proj = (const float*)d_in[4];
  float* out = (float*)d_out;

  char* ws = (char*)d_ws;
  unsigned short* xb  = (unsigned short*)(ws);                    // 12.58 MB
  unsigned short* WaT = (unsigned short*)(ws + 12582912);         //  3.54 MB
  unsigned short* WpT = (unsigned short*)(ws + 16121856);         //  1.18 MB
  unsigned short* qkv = (unsigned short*)(ws + 17301504);         // 37.75 MB
  unsigned short* vt  = (unsigned short*)(ws + 55050240);         // 12.58 MB
  unsigned short* yb  = (unsigned short*)(ws + 67633152);         // 12.58 MB

  const float qscale = 0.10206207261596577f;  // 1/sqrt(96)

  cvt_bf16_kernel<<<(M_ * C_) / 1024, 256, 0, stream>>>(x, xb, M_ * C_);
  w_transpose_kernel<<<dim3(C_ / 32, N1_ / 32), 256, 0, stream>>>(W_attn, WaT, C_, N1_);
  w_transpose_kernel<<<dim3(C_ / 32, C_ / 32), 256, 0, stream>>>(W_proj, WpT, C_, C_);

  // qkv = x @ W_attn + b_attn; Q columns (<768) pre-scaled by 1/sqrt(D).
  // 1-D grid, 64 M-panels: bm = id & 63 -> same-M-panel blocks on one XCD.
  gemm_mfma_kernel<4, false><<<(N1_ / 128) * (M_ / 128), 256, 0, stream>>>(
      xb, WaT, b_attn, qkv, N1_, C_, C_, qscale, 63, 6);
  v_transpose_kernel<<<dim3(M_ / 64, 24), 256, 0, stream>>>(qkv, vt);
  // attn: 1-D grid, bh = id & 63 -> per-(b,h) K/V stays on one XCD's L2
  attn_mfma_kernel<<<8 * B_ * H_, 256, 0, stream>>>(qkv, vt, yb);
  // proj: 64x128 tiles, 128 M-panels: bm = id & 127
  gemm_mfma_kernel<2, true><<<(C_ / 128) * (M_ / 64), 256, 0, stream>>>(
      yb, WpT, b_proj, out, C_, C_, 0, 1.f, 127, 7);
}